// Round 9
// baseline (16.562 us; speedup 1.0000x reference)
//
#include <hip/hip_runtime.h>

// Problem geometry (fixed by reference):
//   x: (32, 3, 224, 224) f32, target: (32,) i32, W: (60,3,1,1) f32, b: (60,) f32
//   out: (32, 3, 224, 224) f32
#define HW    50176   // 224*224
#define HW4   12544   // HW/4 (float4 granules per channel)
#define NB    32      // batch
#define BPN   49      // blocks per sample: 12544 / 256
#define NTHR  256
#define FINF  __int_as_float(0x7f800000)

// Native clang vector type — required by __builtin_nontemporal_{load,store}.
typedef float nfloat4 __attribute__((ext_vector_type(4)));

// ws layout (no initialization required — poison-tolerant):
//   u64 part[1568][3]  : per-block packed {enc(max)<<32 | enc(min)} per channel (37,632 B)
//   u32 cnt[32][16]    : per-sample arrival counters, 64B padded, at +37696   (2 KB)
//        -> never reset; "last block" test is (old % 49 == 48), which fires for
//           exactly one block per sample per call regardless of the counter's
//           base value (graph serializes dispatches; increments are +1 each).
//   f32 finals[32][16] : [0..2]=min, [3..5]=max per sample, at +39744         (2 KB)
//        -> written every call by the last block before pass 2 reads them.

__device__ __forceinline__ unsigned encf(float f) {
    unsigned u = __float_as_uint(f);
    return (u & 0x80000000u) ? ~u : (u | 0x80000000u);
}
__device__ __forceinline__ float decf(unsigned k) {
    unsigned u = (k & 0x80000000u) ? (k & 0x7FFFFFFFu) : ~k;
    return __uint_as_float(u);
}

__global__ __launch_bounds__(NTHR) void pass1_kernel(
    const float* __restrict__ x, const int* __restrict__ target,
    const float* __restrict__ W, const float* __restrict__ b,
    unsigned long long* __restrict__ part, unsigned* __restrict__ cnt,
    float* __restrict__ finals)
{
    const int blk   = blockIdx.x;
    const int n     = blk / BPN;
    const int chunk = blk % BPN;
    const int idx4  = chunk * NTHR + threadIdx.x;   // [0, HW4)
    const int tid   = threadIdx.x;

    // Cached loads: pass 2 re-reads x from L2/L3.
    const nfloat4* xb = (const nfloat4*)(x + (size_t)n * 3 * HW);
    nfloat4 x0 = xb[idx4];
    nfloat4 x1 = xb[idx4 + HW4];
    nfloat4 x2 = xb[idx4 + 2 * HW4];

    const int t = target[n];

    float mn[3], mx[3];
#pragma unroll
    for (int k = 0; k < 3; ++k) {
        const int oc = t * 3 + k;
        const float w0 = W[oc * 3 + 0];
        const float w1 = W[oc * 3 + 1];
        const float w2 = W[oc * 3 + 2];
        const float bk = b[oc];
        float p0 = fmaf(w0, x0.x, fmaf(w1, x1.x, fmaf(w2, x2.x, bk)));
        float p1 = fmaf(w0, x0.y, fmaf(w1, x1.y, fmaf(w2, x2.y, bk)));
        float p2 = fmaf(w0, x0.z, fmaf(w1, x1.z, fmaf(w2, x2.z, bk)));
        float p3 = fmaf(w0, x0.w, fmaf(w1, x1.w, fmaf(w2, x2.w, bk)));
        mn[k] = fminf(fminf(p0, p1), fminf(p2, p3));
        mx[k] = fmaxf(fmaxf(p0, p1), fmaxf(p2, p3));
    }

    // wave-64 butterfly reduce
#pragma unroll
    for (int off = 32; off >= 1; off >>= 1) {
#pragma unroll
        for (int k = 0; k < 3; ++k) {
            mn[k] = fminf(mn[k], __shfl_xor(mn[k], off, 64));
            mx[k] = fmaxf(mx[k], __shfl_xor(mx[k], off, 64));
        }
    }

    __shared__ float smn[4][3], smx[4][3];
    __shared__ int   s_last;
    const int lane = tid & 63;
    const int wave = tid >> 6;
    if (lane == 0) {
#pragma unroll
        for (int k = 0; k < 3; ++k) { smn[wave][k] = mn[k]; smx[wave][k] = mx[k]; }
    }
    __syncthreads();

    // Publish block partial (agent-scope, write-through to coherence point),
    // then arrive. Last arriver (old%49==48) does the per-sample final reduce.
    if (tid == 0) {
        unsigned long long* slot = part + (size_t)blk * 3;
#pragma unroll
        for (int k = 0; k < 3; ++k) {
            float m = fminf(fminf(smn[0][k], smn[1][k]), fminf(smn[2][k], smn[3][k]));
            float M = fmaxf(fmaxf(smx[0][k], smx[1][k]), fmaxf(smx[2][k], smx[3][k]));
            unsigned long long v =
                ((unsigned long long)encf(M) << 32) | (unsigned long long)encf(m);
            __hip_atomic_store(&slot[k], v, __ATOMIC_RELAXED, __HIP_MEMORY_SCOPE_AGENT);
        }
        asm volatile("s_waitcnt vmcnt(0)" ::: "memory");  // partials at L3 before arrival
        unsigned old = __hip_atomic_fetch_add(cnt + n * 16, 1u,
                                              __ATOMIC_RELAXED, __HIP_MEMORY_SCOPE_AGENT);
        s_last = ((old % BPN) == (BPN - 1)) ? 1 : 0;
    }
    __syncthreads();

    if (s_last && tid < 64) {
        // lanes 0..48 gather one partial each (agent loads -> L3, never stale)
        float gmn[3] = { FINF,  FINF,  FINF};
        float gmx[3] = {-FINF, -FINF, -FINF};
        if (tid < BPN) {
            const unsigned long long* p = part + (size_t)(n * BPN + tid) * 3;
#pragma unroll
            for (int k = 0; k < 3; ++k) {
                unsigned long long v =
                    __hip_atomic_load(&p[k], __ATOMIC_RELAXED, __HIP_MEMORY_SCOPE_AGENT);
                gmn[k] = decf((unsigned)(v & 0xFFFFFFFFu));
                gmx[k] = decf((unsigned)(v >> 32));
            }
        }
#pragma unroll
        for (int off = 32; off >= 1; off >>= 1) {
#pragma unroll
            for (int k = 0; k < 3; ++k) {
                gmn[k] = fminf(gmn[k], __shfl_xor(gmn[k], off, 64));
                gmx[k] = fmaxf(gmx[k], __shfl_xor(gmx[k], off, 64));
            }
        }
        if (tid == 0) {
            float* f = finals + n * 16;
#pragma unroll
            for (int k = 0; k < 3; ++k) { f[k] = gmn[k]; f[k + 3] = gmx[k]; }
            // plain stores: end-of-kernel release makes them visible to pass 2
        }
    }
}

__global__ __launch_bounds__(NTHR) void pass2_kernel(
    const float* __restrict__ x, const int* __restrict__ target,
    const float* __restrict__ W, const float* __restrict__ b,
    const float* __restrict__ finals, float* __restrict__ out)
{
    const int blk   = blockIdx.x;
    const int n     = blk / BPN;
    const int chunk = blk % BPN;
    const int idx4  = chunk * NTHR + threadIdx.x;

    // Last use of x: nontemporal loads (comes from L2/L3, evict-hint).
    const nfloat4* xb = (const nfloat4*)(x + (size_t)n * 3 * HW);
    nfloat4 x0 = __builtin_nontemporal_load(&xb[idx4]);
    nfloat4 x1 = __builtin_nontemporal_load(&xb[idx4 + HW4]);
    nfloat4 x2 = __builtin_nontemporal_load(&xb[idx4 + 2 * HW4]);

    // Uniform per block -> scalar (s_load) broadcast; L2/L3-hot. No LDS, no sync.
    const float* f = finals + n * 16;
    const int t = target[n];

#pragma unroll
    for (int k = 0; k < 3; ++k) {
        const int oc = t * 3 + k;
        const float w0 = W[oc * 3 + 0];
        const float w1 = W[oc * 3 + 1];
        const float w2 = W[oc * 3 + 2];
        const float bk = b[oc];
        const float pmin = f[k];
        const float inv  = 1.0f / (f[k + 3] - pmin);

        float p0 = fmaf(w0, x0.x, fmaf(w1, x1.x, fmaf(w2, x2.x, bk)));
        float p1 = fmaf(w0, x0.y, fmaf(w1, x1.y, fmaf(w2, x2.y, bk)));
        float p2 = fmaf(w0, x0.z, fmaf(w1, x1.z, fmaf(w2, x2.z, bk)));
        float p3 = fmaf(w0, x0.w, fmaf(w1, x1.w, fmaf(w2, x2.w, bk)));

        nfloat4 o;
        o.x = ((p0 - pmin) * inv - 0.5f) * 2.0f;
        o.y = ((p1 - pmin) * inv - 0.5f) * 2.0f;
        o.z = ((p2 - pmin) * inv - 0.5f) * 2.0f;
        o.w = ((p3 - pmin) * inv - 0.5f) * 2.0f;
        // MAX_PERTURBATION / 128.0 == 1.0 — no extra scale needed.

        // out never re-read: streaming stores keep L2/L3 for x.
        nfloat4* ob = (nfloat4*)(out + (size_t)n * 3 * HW + (size_t)k * HW);
        __builtin_nontemporal_store(o, &ob[idx4]);
    }
}

extern "C" void kernel_launch(void* const* d_in, const int* in_sizes, int n_in,
                              void* d_out, int out_size, void* d_ws, size_t ws_size,
                              hipStream_t stream) {
    const float* x      = (const float*)d_in[0];
    const int*   target = (const int*)d_in[1];
    const float* W      = (const float*)d_in[2];
    const float* b      = (const float*)d_in[3];
    float*       out    = (float*)d_out;

    unsigned long long* part   = (unsigned long long*)d_ws;            // 37,632 B
    unsigned*           cnt    = (unsigned*)((char*)d_ws + 37696);     // 2 KB
    float*              finals = (float*)((char*)d_ws + 39744);       // 2 KB

    dim3 grid(NB * BPN);
    pass1_kernel<<<grid, NTHR, 0, stream>>>(x, target, W, b, part, cnt, finals);
    pass2_kernel<<<grid, NTHR, 0, stream>>>(x, target, W, b, finals, out);
}

// Round 10
// 14.736 us; speedup vs baseline: 1.1239x; 1.1239x over previous
//
#include <hip/hip_runtime.h>

// Problem geometry (fixed by reference):
//   x: (32, 3, 224, 224) f32, target: (32,) i32, W: (60,3,1,1) f32, b: (60,) f32
//   out: (32, 3, 224, 224) f32
#define HW    50176   // 224*224
#define HW4   12544   // HW/4 (float4 granules per channel)
#define NB    32      // batch
#define NTHR  448     // 7 waves per block
#define GPT   2       // float4 granules per thread per channel
#define BPN   14      // blocks per sample: 12544 / (448*2)
#define FINF  __int_as_float(0x7f800000)

// Native clang vector type — required by __builtin_nontemporal_{load,store}.
typedef float nfloat4 __attribute__((ext_vector_type(4)));

// ws layout: 6 floats per block: [min0,min1,min2,max0,max1,max2]
// All 448*6 slots unconditionally written by pass 1 every call -> no init,
// deterministic across graph replays.

__global__ __launch_bounds__(NTHR) void pass1_kernel(
    const float* __restrict__ x, const int* __restrict__ target,
    const float* __restrict__ W, const float* __restrict__ b,
    float* __restrict__ ws)
{
    const int blk   = blockIdx.x;
    const int n     = blk / BPN;
    const int chunk = blk % BPN;
    const int g0    = chunk * (NTHR * GPT) + threadIdx.x;  // granule A
    const int g1    = g0 + NTHR;                           // granule B

    // Cached loads: populate L2 for pass 2's same-XCD re-read.
    const nfloat4* xb = (const nfloat4*)(x + (size_t)n * 3 * HW);
    nfloat4 a0 = xb[g0];
    nfloat4 a1 = xb[g0 + HW4];
    nfloat4 a2 = xb[g0 + 2 * HW4];
    nfloat4 c0 = xb[g1];
    nfloat4 c1 = xb[g1 + HW4];
    nfloat4 c2 = xb[g1 + 2 * HW4];

    const int t = target[n];

    float mn[3], mx[3];
#pragma unroll
    for (int k = 0; k < 3; ++k) {
        const int oc = t * 3 + k;
        const float w0 = W[oc * 3 + 0];
        const float w1 = W[oc * 3 + 1];
        const float w2 = W[oc * 3 + 2];
        const float bk = b[oc];
        float p0 = fmaf(w0, a0.x, fmaf(w1, a1.x, fmaf(w2, a2.x, bk)));
        float p1 = fmaf(w0, a0.y, fmaf(w1, a1.y, fmaf(w2, a2.y, bk)));
        float p2 = fmaf(w0, a0.z, fmaf(w1, a1.z, fmaf(w2, a2.z, bk)));
        float p3 = fmaf(w0, a0.w, fmaf(w1, a1.w, fmaf(w2, a2.w, bk)));
        float q0 = fmaf(w0, c0.x, fmaf(w1, c1.x, fmaf(w2, c2.x, bk)));
        float q1 = fmaf(w0, c0.y, fmaf(w1, c1.y, fmaf(w2, c2.y, bk)));
        float q2 = fmaf(w0, c0.z, fmaf(w1, c1.z, fmaf(w2, c2.z, bk)));
        float q3 = fmaf(w0, c0.w, fmaf(w1, c1.w, fmaf(w2, c2.w, bk)));
        mn[k] = fminf(fminf(fminf(p0, p1), fminf(p2, p3)),
                      fminf(fminf(q0, q1), fminf(q2, q3)));
        mx[k] = fmaxf(fmaxf(fmaxf(p0, p1), fmaxf(p2, p3)),
                      fmaxf(fmaxf(q0, q1), fmaxf(q2, q3)));
    }

    // wave-64 butterfly reduce
#pragma unroll
    for (int off = 32; off >= 1; off >>= 1) {
#pragma unroll
        for (int k = 0; k < 3; ++k) {
            mn[k] = fminf(mn[k], __shfl_xor(mn[k], off, 64));
            mx[k] = fmaxf(mx[k], __shfl_xor(mx[k], off, 64));
        }
    }

    __shared__ float smn[7][3], smx[7][3];
    const int lane = threadIdx.x & 63;
    const int wave = threadIdx.x >> 6;
    if (lane == 0) {
#pragma unroll
        for (int k = 0; k < 3; ++k) { smn[wave][k] = mn[k]; smx[wave][k] = mx[k]; }
    }
    __syncthreads();
    if (threadIdx.x == 0) {
        float* dst = ws + (size_t)blk * 6;
#pragma unroll
        for (int k = 0; k < 3; ++k) {
            float m = smn[0][k], M = smx[0][k];
#pragma unroll
            for (int w = 1; w < 7; ++w) { m = fminf(m, smn[w][k]); M = fmaxf(M, smx[w][k]); }
            dst[k]     = m;
            dst[k + 3] = M;
        }
    }
}

__global__ __launch_bounds__(NTHR) void pass2_kernel(
    const float* __restrict__ x, const int* __restrict__ target,
    const float* __restrict__ W, const float* __restrict__ b,
    const float* __restrict__ ws, float* __restrict__ out)
{
    const int blk   = blockIdx.x;
    const int n     = blk / BPN;
    const int chunk = blk % BPN;
    const int g0    = chunk * (NTHR * GPT) + threadIdx.x;
    const int g1    = g0 + NTHR;

    // Cached loads: same-XCD L2 hit (pass 1 block i == pass 2 block i mapping).
    const nfloat4* xb = (const nfloat4*)(x + (size_t)n * 3 * HW);
    nfloat4 a0 = xb[g0];
    nfloat4 a1 = xb[g0 + HW4];
    nfloat4 a2 = xb[g0 + 2 * HW4];
    nfloat4 c0 = xb[g1];
    nfloat4 c1 = xb[g1 + HW4];
    nfloat4 c2 = xb[g1 + 2 * HW4];

    // Reduce this sample's 14 block-partials (L2-resident, 336 B).
    __shared__ float s_min[3], s_max[3];
    if (threadIdx.x < 64) {
        const int lane = threadIdx.x;
        float mn[3] = { FINF,  FINF,  FINF};
        float mx[3] = {-FINF, -FINF, -FINF};
        if (lane < BPN) {
            const float* p = ws + (size_t)(n * BPN + lane) * 6;
#pragma unroll
            for (int k = 0; k < 3; ++k) { mn[k] = p[k]; mx[k] = p[k + 3]; }
        }
#pragma unroll
        for (int off = 8; off >= 1; off >>= 1) {   // 14 values live in lanes 0..15
#pragma unroll
            for (int k = 0; k < 3; ++k) {
                mn[k] = fminf(mn[k], __shfl_xor(mn[k], off, 64));
                mx[k] = fmaxf(mx[k], __shfl_xor(mx[k], off, 64));
            }
        }
        if (lane == 0) {
#pragma unroll
            for (int k = 0; k < 3; ++k) { s_min[k] = mn[k]; s_max[k] = mx[k]; }
        }
    }
    __syncthreads();

    const int t = target[n];

#pragma unroll
    for (int k = 0; k < 3; ++k) {
        const int oc = t * 3 + k;
        const float w0 = W[oc * 3 + 0];
        const float w1 = W[oc * 3 + 1];
        const float w2 = W[oc * 3 + 2];
        const float bk = b[oc];
        const float pmin = s_min[k];
        const float inv  = 1.0f / (s_max[k] - pmin);

        nfloat4 o, q;
        o.x = ((fmaf(w0, a0.x, fmaf(w1, a1.x, fmaf(w2, a2.x, bk))) - pmin) * inv - 0.5f) * 2.0f;
        o.y = ((fmaf(w0, a0.y, fmaf(w1, a1.y, fmaf(w2, a2.y, bk))) - pmin) * inv - 0.5f) * 2.0f;
        o.z = ((fmaf(w0, a0.z, fmaf(w1, a1.z, fmaf(w2, a2.z, bk))) - pmin) * inv - 0.5f) * 2.0f;
        o.w = ((fmaf(w0, a0.w, fmaf(w1, a1.w, fmaf(w2, a2.w, bk))) - pmin) * inv - 0.5f) * 2.0f;
        q.x = ((fmaf(w0, c0.x, fmaf(w1, c1.x, fmaf(w2, c2.x, bk))) - pmin) * inv - 0.5f) * 2.0f;
        q.y = ((fmaf(w0, c0.y, fmaf(w1, c1.y, fmaf(w2, c2.y, bk))) - pmin) * inv - 0.5f) * 2.0f;
        q.z = ((fmaf(w0, c0.z, fmaf(w1, c1.z, fmaf(w2, c2.z, bk))) - pmin) * inv - 0.5f) * 2.0f;
        q.w = ((fmaf(w0, c0.w, fmaf(w1, c1.w, fmaf(w2, c2.w, bk))) - pmin) * inv - 0.5f) * 2.0f;
        // MAX_PERTURBATION / 128.0 == 1.0 — no extra scale needed.

        // out never re-read: streaming stores (no write-allocate).
        nfloat4* ob = (nfloat4*)(out + (size_t)n * 3 * HW + (size_t)k * HW);
        __builtin_nontemporal_store(o, &ob[g0]);
        __builtin_nontemporal_store(q, &ob[g1]);
    }
}

extern "C" void kernel_launch(void* const* d_in, const int* in_sizes, int n_in,
                              void* d_out, int out_size, void* d_ws, size_t ws_size,
                              hipStream_t stream) {
    const float* x      = (const float*)d_in[0];
    const int*   target = (const int*)d_in[1];
    const float* W      = (const float*)d_in[2];
    const float* b      = (const float*)d_in[3];
    float*       out    = (float*)d_out;
    float*       ws     = (float*)d_ws;   // 448 * 6 floats = 10.7 KB

    dim3 grid(NB * BPN);   // 448 blocks
    pass1_kernel<<<grid, NTHR, 0, stream>>>(x, target, W, b, ws);
    pass2_kernel<<<grid, NTHR, 0, stream>>>(x, target, W, b, ws, out);
}